// Round 1
// baseline (146.582 us; speedup 1.0000x reference)
//
#include <hip/hip_runtime.h>

#define TEMP 0.05f
#define EPS 1e-8f
#define NROWS 16384
#define DDIM 1024

#define WAVES_PER_BLOCK 4
#define ROWS_PER_WAVE 4
#define NBLOCKS (NROWS / (WAVES_PER_BLOCK * ROWS_PER_WAVE))   // 1024 blocks
#define NPARTIALS (NROWS / ROWS_PER_WAVE)                      // 4096 partials (16 KB)

__global__ __launch_bounds__(256) void byol_rows_kernel(
        const float* __restrict__ a, const float* __restrict__ b,
        float* __restrict__ partials) {
    const int wave = threadIdx.x >> 6;
    const int lane = threadIdx.x & 63;
    const int wgid = blockIdx.x * WAVES_PER_BLOCK + wave;   // global wave id
    const size_t row0 = (size_t)wgid * ROWS_PER_WAVE;

    float lsum = 0.f;

#pragma unroll
    for (int k = 0; k < ROWS_PER_WAVE; k += 2) {
        const float4* a0 = (const float4*)(a + (row0 + k)     * DDIM);
        const float4* b0 = (const float4*)(b + (row0 + k)     * DDIM);
        const float4* a1 = (const float4*)(a + (row0 + k + 1) * DDIM);
        const float4* b1 = (const float4*)(b + (row0 + k + 1) * DDIM);

        // Issue all 16 loads (256 B/lane in flight) before any dependent math.
        float4 av0[4], bv0[4], av1[4], bv1[4];
#pragma unroll
        for (int j = 0; j < 4; ++j) {
            av0[j] = a0[lane + 64 * j];
            bv0[j] = b0[lane + 64 * j];
            av1[j] = a1[lane + 64 * j];
            bv1[j] = b1[lane + 64 * j];
        }

        float dot0 = 0.f, aa0 = 0.f, bb0 = 0.f;
        float dot1 = 0.f, aa1 = 0.f, bb1 = 0.f;
#pragma unroll
        for (int j = 0; j < 4; ++j) {
            dot0 += av0[j].x * bv0[j].x + av0[j].y * bv0[j].y
                  + av0[j].z * bv0[j].z + av0[j].w * bv0[j].w;
            aa0  += av0[j].x * av0[j].x + av0[j].y * av0[j].y
                  + av0[j].z * av0[j].z + av0[j].w * av0[j].w;
            bb0  += bv0[j].x * bv0[j].x + bv0[j].y * bv0[j].y
                  + bv0[j].z * bv0[j].z + bv0[j].w * bv0[j].w;
            dot1 += av1[j].x * bv1[j].x + av1[j].y * bv1[j].y
                  + av1[j].z * bv1[j].z + av1[j].w * bv1[j].w;
            aa1  += av1[j].x * av1[j].x + av1[j].y * av1[j].y
                  + av1[j].z * av1[j].z + av1[j].w * av1[j].w;
            bb1  += bv1[j].x * bv1[j].x + bv1[j].y * bv1[j].y
                  + bv1[j].z * bv1[j].z + bv1[j].w * bv1[j].w;
        }

        // One shared 6-step butterfly for both rows' 6 accumulators.
#pragma unroll
        for (int off = 32; off > 0; off >>= 1) {
            dot0 += __shfl_down(dot0, off, 64);
            aa0  += __shfl_down(aa0,  off, 64);
            bb0  += __shfl_down(bb0,  off, 64);
            dot1 += __shfl_down(dot1, off, 64);
            aa1  += __shfl_down(aa1,  off, 64);
            bb1  += __shfl_down(bb1,  off, 64);
        }

        if (lane == 0) {
            float c0 = dot0 / (fmaxf(sqrtf(aa0), EPS) * fmaxf(sqrtf(bb0), EPS));
            float c1 = dot1 / (fmaxf(sqrtf(aa1), EPS) * fmaxf(sqrtf(bb1), EPS));
            lsum += (2.0f - 2.0f * c0) + (2.0f - 2.0f * c1);
        }
    }

    // No __syncthreads, no LDS: one store per wave.
    if (lane == 0) partials[wgid] = lsum;
}

__global__ __launch_bounds__(256) void byol_final_kernel(
        const float* __restrict__ partials, float* __restrict__ out) {
    float sum = 0.f;
#pragma unroll
    for (int j = 0; j < NPARTIALS / 256; ++j)
        sum += partials[threadIdx.x + 256 * j];

#pragma unroll
    for (int off = 32; off > 0; off >>= 1)
        sum += __shfl_down(sum, off, 64);

    __shared__ float s[4];
    const int wave = threadIdx.x >> 6;
    const int lane = threadIdx.x & 63;
    if (lane == 0) s[wave] = sum;
    __syncthreads();
    if (threadIdx.x == 0) {
        out[0] = (s[0] + s[1] + s[2] + s[3]) * (1.0f / ((float)NROWS * TEMP));
    }
}

extern "C" void kernel_launch(void* const* d_in, const int* in_sizes, int n_in,
                              void* d_out, int out_size, void* d_ws, size_t ws_size,
                              hipStream_t stream) {
    const float* a = (const float*)d_in[0];
    const float* b = (const float*)d_in[1];
    float* out = (float*)d_out;
    float* partials = (float*)d_ws;   // NPARTIALS floats = 16 KB

    byol_rows_kernel<<<NBLOCKS, 256, 0, stream>>>(a, b, partials);
    byol_final_kernel<<<1, 256, 0, stream>>>(partials, out);
}

// Round 3
// 134.859 us; speedup vs baseline: 1.0869x; 1.0869x over previous
//
#include <hip/hip_runtime.h>

#define TEMP 0.05f
#define EPS 1e-8f
#define NROWS 16384
#define DDIM 1024
#define NBLOCKS (NROWS / 4)   // 4 waves/block, 1 row/wave (round-0 geometry)

typedef float vf4 __attribute__((ext_vector_type(4)));

__global__ __launch_bounds__(256) void byol_rows_kernel(
        const float* __restrict__ a, const float* __restrict__ b,
        float* __restrict__ partials) {
    const int wave = threadIdx.x >> 6;
    const int lane = threadIdx.x & 63;
    const int row  = blockIdx.x * 4 + wave;

    const vf4* a4 = (const vf4*)(a + (size_t)row * DDIM);
    const vf4* b4 = (const vf4*)(b + (size_t)row * DDIM);

    // Phase 1: issue ALL 8 loads (128 B/lane) before any dependent math.
    // Nontemporal: bypass L1 allocation on this streaming, zero-reuse read.
    vf4 av[4], bv[4];
#pragma unroll
    for (int j = 0; j < 4; ++j)
        av[j] = __builtin_nontemporal_load(&a4[lane + 64 * j]);
#pragma unroll
    for (int j = 0; j < 4; ++j)
        bv[j] = __builtin_nontemporal_load(&b4[lane + 64 * j]);

    // Phase 2: accumulate.
    float dot = 0.f, aa = 0.f, bb = 0.f;
#pragma unroll
    for (int j = 0; j < 4; ++j) {
        dot += av[j].x * bv[j].x + av[j].y * bv[j].y
             + av[j].z * bv[j].z + av[j].w * bv[j].w;
        aa  += av[j].x * av[j].x + av[j].y * av[j].y
             + av[j].z * av[j].z + av[j].w * av[j].w;
        bb  += bv[j].x * bv[j].x + bv[j].y * bv[j].y
             + bv[j].z * bv[j].z + bv[j].w * bv[j].w;
    }

    // Phase 3: wave butterfly reduce.
#pragma unroll
    for (int off = 32; off > 0; off >>= 1) {
        dot += __shfl_down(dot, off, 64);
        aa  += __shfl_down(aa,  off, 64);
        bb  += __shfl_down(bb,  off, 64);
    }

    __shared__ float s[4];
    if (lane == 0) {
        float n1 = fmaxf(sqrtf(aa), EPS);
        float n2 = fmaxf(sqrtf(bb), EPS);
        float c  = dot / (n1 * n2);
        s[wave]  = 2.0f - 2.0f * c;
    }
    __syncthreads();
    if (threadIdx.x == 0) {
        partials[blockIdx.x] = s[0] + s[1] + s[2] + s[3];
    }
}

__global__ __launch_bounds__(256) void byol_final_kernel(
        const float* __restrict__ partials, float* __restrict__ out) {
    float sum = 0.f;
#pragma unroll
    for (int j = 0; j < NBLOCKS / 256; ++j)
        sum += partials[threadIdx.x + 256 * j];

#pragma unroll
    for (int off = 32; off > 0; off >>= 1)
        sum += __shfl_down(sum, off, 64);

    __shared__ float s[4];
    const int wave = threadIdx.x >> 6;
    const int lane = threadIdx.x & 63;
    if (lane == 0) s[wave] = sum;
    __syncthreads();
    if (threadIdx.x == 0) {
        out[0] = (s[0] + s[1] + s[2] + s[3]) * (1.0f / ((float)NROWS * TEMP));
    }
}

extern "C" void kernel_launch(void* const* d_in, const int* in_sizes, int n_in,
                              void* d_out, int out_size, void* d_ws, size_t ws_size,
                              hipStream_t stream) {
    const float* a = (const float*)d_in[0];
    const float* b = (const float*)d_in[1];
    float* out = (float*)d_out;
    float* partials = (float*)d_ws;   // NBLOCKS floats = 16 KB

    byol_rows_kernel<<<NBLOCKS, 256, 0, stream>>>(a, b, partials);
    byol_final_kernel<<<1, 256, 0, stream>>>(partials, out);
}